// Round 1
// baseline (491.918 us; speedup 1.0000x reference)
//
#include <hip/hip_runtime.h>

typedef unsigned short u16;
typedef u16 u16x8 __attribute__((ext_vector_type(8)));
typedef u16 u16x4 __attribute__((ext_vector_type(4)));
typedef float f32x4 __attribute__((ext_vector_type(4)));
typedef __bf16 bf16x8 __attribute__((ext_vector_type(8)));

#define SCALE_QK 0.35355339059327373f   /* 64^-0.25 */
#define LAMBDA_INIT 0.7836057665316245f
#define ONE_MINUS_LI 0.21639423346837554f

__device__ __forceinline__ u16 f2bf(float f) {
  unsigned u = __builtin_bit_cast(unsigned, f);
  u = (u + 0x7FFFu + ((u >> 16) & 1u)) >> 16;   // RNE
  return (u16)u;
}
__device__ __forceinline__ float bf2f(u16 h) {
  unsigned u = ((unsigned)h) << 16;
  return __builtin_bit_cast(float, u);
}
__device__ __forceinline__ f32x4 mfma16(bf16x8 a, bf16x8 b, f32x4 c) {
  return __builtin_amdgcn_mfma_f32_16x16x32_bf16(a, b, c, 0, 0, 0);
}

// ---------------- fp32 -> bf16 convert ----------------
__global__ void cvt_f32_bf16_kernel(const float* __restrict__ in, u16* __restrict__ out, int n4) {
  int idx = blockIdx.x * blockDim.x + threadIdx.x;
  if (idx >= n4) return;
  f32x4 v = *(const f32x4*)(in + (size_t)idx * 4);
  u16x4 o;
  o[0] = f2bf(v[0]); o[1] = f2bf(v[1]); o[2] = f2bf(v[2]); o[3] = f2bf(v[3]);
  *(u16x4*)(out + (size_t)idx * 4) = o;
}

// ---------------- RoPE cos/sin table: [s=2048][i=32] ----------------
__global__ void rope_table_kernel(float* __restrict__ cosT, float* __restrict__ sinT) {
  int idx = blockIdx.x * blockDim.x + threadIdx.x;
  if (idx >= 2048 * 32) return;
  int i = idx & 31;
  int t = idx >> 5;
  // inv_freq = 10000^(-i/32) = exp(-i * ln(10000)/32)
  float invf = expf(-(float)i * 0.2878231366242558f);
  float f = (float)t * invf;
  cosT[idx] = cosf(f);
  sinT[idx] = sinf(f);
}

// ---------------- lambda scalar ----------------
__global__ void lam_kernel(const float* __restrict__ lq1, const float* __restrict__ lk1,
                           const float* __restrict__ lq2, const float* __restrict__ lk2,
                           float* __restrict__ out) {
  int l = threadIdx.x & 63;
  float a = lq1[l] * lk1[l];
  float b = lq2[l] * lk2[l];
#pragma unroll
  for (int m = 1; m < 64; m <<= 1) {
    a += __shfl_xor(a, m);
    b += __shfl_xor(b, m);
  }
  if (l == 0) out[0] = expf(a) - expf(b) + LAMBDA_INIT;
}

// ---------------- GEMM C = A @ B^T (A[M][K], B[N][K], bf16 in) ----------------
template<bool F32OUT>
__device__ __forceinline__ void gemm_body(const u16* __restrict__ A, const u16* __restrict__ Bm,
                                          void* __restrict__ C, int M, int N, int K) {
  __shared__ __align__(16) u16 As[128][72];
  __shared__ __align__(16) u16 Bs[128][72];
  const int tid = threadIdx.x;
  const int lane = tid & 63, wid = tid >> 6;
  const int wr = wid >> 1, wc = wid & 1;
  const int c = lane & 15, g = lane >> 4;
  const int bm = blockIdx.x * 128, bn = blockIdx.y * 128;
  const int lrow = tid >> 3;          // 0..31
  const int lcol = (tid & 7) * 8;     // 0..56
  f32x4 acc[4][4];
#pragma unroll
  for (int m = 0; m < 4; ++m)
#pragma unroll
    for (int n = 0; n < 4; ++n) acc[m][n] = (f32x4){0.f, 0.f, 0.f, 0.f};

  for (int k0 = 0; k0 < K; k0 += 64) {
#pragma unroll
    for (int i = 0; i < 4; ++i) {
      int r = lrow + i * 32;
      *(u16x8*)(&As[r][lcol]) = *(const u16x8*)(A + (size_t)(bm + r) * K + k0 + lcol);
      *(u16x8*)(&Bs[r][lcol]) = *(const u16x8*)(Bm + (size_t)(bn + r) * K + k0 + lcol);
    }
    __syncthreads();
#pragma unroll
    for (int kk = 0; kk < 2; ++kk) {
      const int co = kk * 32 + g * 8;
      bf16x8 af[4], bfm[4];
#pragma unroll
      for (int m = 0; m < 4; ++m)
        af[m] = __builtin_bit_cast(bf16x8, *(const u16x8*)(&As[wr * 64 + m * 16 + c][co]));
#pragma unroll
      for (int n = 0; n < 4; ++n)
        bfm[n] = __builtin_bit_cast(bf16x8, *(const u16x8*)(&Bs[wc * 64 + n * 16 + c][co]));
#pragma unroll
      for (int m = 0; m < 4; ++m)
#pragma unroll
        for (int n = 0; n < 4; ++n)
          acc[m][n] = mfma16(af[m], bfm[n], acc[m][n]);
    }
    __syncthreads();
  }
#pragma unroll
  for (int m = 0; m < 4; ++m)
#pragma unroll
    for (int n = 0; n < 4; ++n) {
      const int col = bn + wc * 64 + n * 16 + c;
      const int row0 = bm + wr * 64 + m * 16 + g * 4;
#pragma unroll
      for (int r = 0; r < 4; ++r) {
        if constexpr (F32OUT) ((float*)C)[(size_t)(row0 + r) * N + col] = acc[m][n][r];
        else ((u16*)C)[(size_t)(row0 + r) * N + col] = f2bf(acc[m][n][r]);
      }
    }
}

__global__ __launch_bounds__(256) void gemm_qkv_kernel(
    const u16* __restrict__ A,
    const u16* __restrict__ B0, const u16* __restrict__ B1, const u16* __restrict__ B2,
    u16* __restrict__ C0, u16* __restrict__ C1, u16* __restrict__ C2) {
  const u16* Bm = (blockIdx.z == 0) ? B0 : (blockIdx.z == 1) ? B1 : B2;
  u16* C = (blockIdx.z == 0) ? C0 : (blockIdx.z == 1) ? C1 : C2;
  gemm_body<false>(A, Bm, C, 4096, 1024, 1024);
}

__global__ __launch_bounds__(256) void gemm_f32_kernel(const u16* __restrict__ A,
                                                       const u16* __restrict__ Bm,
                                                       float* __restrict__ C) {
  gemm_body<true>(A, Bm, C, 4096, 1024, 1024);
}

// ---------------- RoPE in-place on [b][s][16][64] bf16 ----------------
__global__ void rope_kernel(u16* __restrict__ X, const float* __restrict__ cosT,
                            const float* __restrict__ sinT) {
  int idx = blockIdx.x * blockDim.x + threadIdx.x;
  if (idx >= 2 * 2048 * 16 * 8) return;
  int seg = idx & 7;
  int head2 = (idx >> 3) & 15;
  int s = (idx >> 7) & 2047;
  int b = idx >> 18;
  size_t base = (((size_t)(b * 2048 + s)) * 16 + head2) * 64 + seg * 8;
  u16x8 v = *(const u16x8*)(X + base);
  u16x8 o;
#pragma unroll
  for (int j = 0; j < 4; ++j) {
    int i = seg * 4 + j;
    float cc = cosT[s * 32 + i];
    float sn = sinT[s * 32 + i];
    float xe = bf2f(v[2 * j]);
    float xo = bf2f(v[2 * j + 1]);
    o[2 * j]     = f2bf(xe * cc - xo * sn);
    o[2 * j + 1] = f2bf(xo * cc + xe * sn);
  }
  *(u16x8*)(X + base) = o;
}

// ---------------- V transpose: [b][s][h*128+d] -> Vt[(b*8+h)*128+d][s] ----------------
__global__ __launch_bounds__(256) void transpose_v_kernel(const u16* __restrict__ V,
                                                          u16* __restrict__ Vt) {
  __shared__ __align__(16) u16 tile[64][136];
  const int s0 = blockIdx.x * 64;
  const int bh = blockIdx.y;           // b*8 + h
  const int b = bh >> 3, h = bh & 7;
  const int t = threadIdx.x;
  {
    const int dseg = (t & 15) * 8;
    const int sl = t >> 4;             // 0..15
#pragma unroll
    for (int it = 0; it < 4; ++it) {
      int srow = sl + it * 16;
      u16x8 v = *(const u16x8*)(V + (size_t)((b * 2048) + s0 + srow) * 1024 + h * 128 + dseg);
      *(u16x8*)(&tile[srow][dseg]) = v;
    }
  }
  __syncthreads();
  {
    const int sseg = (t & 7) * 8;
    const int dl = t >> 3;             // 0..31
#pragma unroll
    for (int it = 0; it < 4; ++it) {
      int d = dl + it * 32;
      u16x8 o;
#pragma unroll
      for (int r = 0; r < 8; ++r) o[r] = tile[sseg + r][d];
      *(u16x8*)(Vt + ((size_t)bh * 128 + d) * 2048 + s0 + sseg) = o;
    }
  }
}

// ---------------- fused flash diff-attention ----------------
// grid (32 q-tiles, 16 bh). 4 waves; wave owns 16 q-rows. Both paths per block.
__global__ __launch_bounds__(256) void attn_kernel(
    const u16* __restrict__ Qb, const u16* __restrict__ Kb, const u16* __restrict__ Vt,
    const float* __restrict__ lamp, const float* __restrict__ lnw, const float* __restrict__ lnb,
    u16* __restrict__ Oc) {
  __shared__ __align__(16) u16 p_lds[4][16][72];
  const int tid = threadIdx.x;
  const int lane = tid & 63;
  const int wid = tid >> 6;
  const int c = lane & 15;
  const int g = lane >> 4;
  const int qt = blockIdx.x;
  const int bh = blockIdx.y;
  const int b = bh >> 3, h = bh & 7;
  const int qrow = qt * 64 + wid * 16;

  f32x4 oacc[2][8];
  float Lden[2][4];

#pragma unroll
  for (int p = 0; p < 2; ++p) {
    const int head2 = 2 * h + p;
    const u16* qbase = Qb + ((size_t)((b * 2048) + qrow + c) * 16 + head2) * 64 + g * 8;
    bf16x8 qf0 = __builtin_bit_cast(bf16x8, *(const u16x8*)(qbase));
    bf16x8 qf1 = __builtin_bit_cast(bf16x8, *(const u16x8*)(qbase + 32));
    const u16* kbase = Kb + (size_t)b * 2048 * 1024 + head2 * 64 + g * 8;
    const u16* vbase = Vt + ((size_t)bh * 128 + c) * 2048 + g * 8;

    f32x4 acc[8];
#pragma unroll
    for (int i = 0; i < 8; ++i) acc[i] = (f32x4){0.f, 0.f, 0.f, 0.f};
    float mrow[4] = {-1e30f, -1e30f, -1e30f, -1e30f};
    float Lrow[4] = {0.f, 0.f, 0.f, 0.f};

    for (int k0 = 0; k0 < 2048; k0 += 64) {
      f32x4 sacc[4];
#pragma unroll
      for (int n = 0; n < 4; ++n) sacc[n] = (f32x4){0.f, 0.f, 0.f, 0.f};
#pragma unroll
      for (int n = 0; n < 4; ++n) {
        const u16* kr = kbase + (size_t)(k0 + n * 16 + c) * 1024;
        bf16x8 kf0 = __builtin_bit_cast(bf16x8, *(const u16x8*)(kr));
        bf16x8 kf1 = __builtin_bit_cast(bf16x8, *(const u16x8*)(kr + 32));
        sacc[n] = mfma16(qf0, kf0, sacc[n]);
        sacc[n] = mfma16(qf1, kf1, sacc[n]);
      }
      float pv[4][4];
      float alpha[4];
#pragma unroll
      for (int r = 0; r < 4; ++r) {
        float s0 = sacc[0][r] * SCALE_QK, s1 = sacc[1][r] * SCALE_QK;
        float s2 = sacc[2][r] * SCALE_QK, s3 = sacc[3][r] * SCALE_QK;
        float mx = fmaxf(fmaxf(s0, s1), fmaxf(s2, s3));
        mx = fmaxf(mx, __shfl_xor(mx, 1));
        mx = fmaxf(mx, __shfl_xor(mx, 2));
        mx = fmaxf(mx, __shfl_xor(mx, 4));
        mx = fmaxf(mx, __shfl_xor(mx, 8));
        float mnew = fmaxf(mrow[r], mx);
        float al = __expf(mrow[r] - mnew);
        float p0 = __expf(s0 - mnew), p1 = __expf(s1 - mnew);
        float p2 = __expf(s2 - mnew), p3 = __expf(s3 - mnew);
        pv[0][r] = p0; pv[1][r] = p1; pv[2][r] = p2; pv[3][r] = p3;
        float sum = p0 + p1 + p2 + p3;
        sum += __shfl_xor(sum, 1);
        sum += __shfl_xor(sum, 2);
        sum += __shfl_xor(sum, 4);
        sum += __shfl_xor(sum, 8);
        Lrow[r] = Lrow[r] * al + sum;
        mrow[r] = mnew;
        alpha[r] = al;
      }
#pragma unroll
      for (int i = 0; i < 8; ++i) {
#pragma unroll
        for (int r = 0; r < 4; ++r) acc[i][r] *= alpha[r];
      }
#pragma unroll
      for (int n = 0; n < 4; ++n)
#pragma unroll
        for (int r = 0; r < 4; ++r)
          p_lds[wid][g * 4 + r][n * 16 + c] = f2bf(pv[n][r]);
      // wave-private LDS region: compiler-inserted lgkmcnt ordering suffices
#pragma unroll
      for (int ks = 0; ks < 2; ++ks) {
        bf16x8 pf = __builtin_bit_cast(bf16x8, *(const u16x8*)(&p_lds[wid][c][ks * 32 + g * 8]));
#pragma unroll
        for (int nO = 0; nO < 8; ++nO) {
          bf16x8 vf = __builtin_bit_cast(bf16x8,
              *(const u16x8*)(vbase + (size_t)(nO * 16) * 2048 + k0 + ks * 32));
          acc[nO] = mfma16(pf, vf, acc[nO]);
        }
      }
    }
#pragma unroll
    for (int i = 0; i < 8; ++i) oacc[p][i] = acc[i];
#pragma unroll
    for (int r = 0; r < 4; ++r) Lden[p][r] = Lrow[r];
  }

  const float lam = lamp[0];
  float lw[8], lb[8];
#pragma unroll
  for (int nO = 0; nO < 8; ++nO) {
    lw[nO] = lnw[nO * 16 + c];
    lb[nO] = lnb[nO * 16 + c];
  }
#pragma unroll
  for (int r = 0; r < 4; ++r) {
    float inv1 = 1.f / Lden[0][r], inv2 = 1.f / Lden[1][r];
    float vals[8];
    float ss = 0.f;
#pragma unroll
    for (int nO = 0; nO < 8; ++nO) {
      float v = oacc[0][nO][r] * inv1 - lam * (oacc[1][nO][r] * inv2);
      vals[nO] = v;
      ss += v * v;
    }
    ss += __shfl_xor(ss, 1);
    ss += __shfl_xor(ss, 2);
    ss += __shfl_xor(ss, 4);
    ss += __shfl_xor(ss, 8);
    float rinv = rsqrtf(ss * (1.0f / 128.0f) + 1e-8f);
    int srow = b * 2048 + qt * 64 + wid * 16 + g * 4 + r;
#pragma unroll
    for (int nO = 0; nO < 8; ++nO) {
      float v = (vals[nO] * rinv * lw[nO] + lb[nO]) * ONE_MINUS_LI;
      Oc[(size_t)srow * 1024 + h * 128 + nO * 16 + c] = f2bf(v);
    }
  }
}

extern "C" void kernel_launch(void* const* d_in, const int* in_sizes, int n_in,
                              void* d_out, int out_size, void* d_ws, size_t ws_size,
                              hipStream_t stream) {
  const float* x   = (const float*)d_in[0];
  const float* Wq  = (const float*)d_in[1];
  const float* Wk  = (const float*)d_in[2];
  const float* Wv  = (const float*)d_in[3];
  const float* Wo  = (const float*)d_in[4];
  const float* lq1 = (const float*)d_in[5];
  const float* lk1 = (const float*)d_in[6];
  const float* lq2 = (const float*)d_in[7];
  const float* lk2 = (const float*)d_in[8];
  const float* lnw = (const float*)d_in[9];
  const float* lnb = (const float*)d_in[10];

  char* w = (char*)d_ws;
  size_t off = 0;
  auto alloc = [&](size_t bytes) {
    char* p = w + off;
    off = (off + bytes + 255) & ~(size_t)255;
    return p;
  };
  u16* xb   = (u16*)alloc(4096ull * 1024 * 2);
  u16* wqb  = (u16*)alloc(1024ull * 1024 * 2);
  u16* wkb  = (u16*)alloc(1024ull * 1024 * 2);
  u16* wvb  = (u16*)alloc(1024ull * 1024 * 2);
  u16* wob  = (u16*)alloc(1024ull * 1024 * 2);
  u16* Qb   = (u16*)alloc(4096ull * 1024 * 2);
  u16* Kb   = (u16*)alloc(4096ull * 1024 * 2);
  u16* Vb   = (u16*)alloc(4096ull * 1024 * 2);
  u16* Vt   = (u16*)alloc(4096ull * 1024 * 2);
  u16* Ocb  = (u16*)alloc(4096ull * 1024 * 2);
  float* cosT = (float*)alloc(2048ull * 32 * 4);
  float* sinT = (float*)alloc(2048ull * 32 * 4);
  float* lamp = (float*)alloc(256);

  // converts
  cvt_f32_bf16_kernel<<<4096, 256, 0, stream>>>(x, xb, 4096 * 1024 / 4);
  cvt_f32_bf16_kernel<<<1024, 256, 0, stream>>>(Wq, wqb, 1024 * 1024 / 4);
  cvt_f32_bf16_kernel<<<1024, 256, 0, stream>>>(Wk, wkb, 1024 * 1024 / 4);
  cvt_f32_bf16_kernel<<<1024, 256, 0, stream>>>(Wv, wvb, 1024 * 1024 / 4);
  cvt_f32_bf16_kernel<<<1024, 256, 0, stream>>>(Wo, wob, 1024 * 1024 / 4);
  rope_table_kernel<<<256, 256, 0, stream>>>(cosT, sinT);
  lam_kernel<<<1, 64, 0, stream>>>(lq1, lk1, lq2, lk2, lamp);

  // QKV projections (fused via grid.z)
  gemm_qkv_kernel<<<dim3(32, 8, 3), 256, 0, stream>>>(xb, wqb, wkb, wvb, Qb, Kb, Vb);

  // RoPE on Q and K
  rope_kernel<<<2048, 256, 0, stream>>>(Qb, cosT, sinT);
  rope_kernel<<<2048, 256, 0, stream>>>(Kb, cosT, sinT);

  // V transpose for PV fragment layout
  transpose_v_kernel<<<dim3(32, 16), 256, 0, stream>>>(Vb, Vt);

  // fused diff flash attention + RMS norm
  attn_kernel<<<dim3(32, 16), 256, 0, stream>>>(Qb, Kb, Vt, lamp, lnw, lnb, Ocb);

  // output projection
  gemm_f32_kernel<<<dim3(32, 8), 256, 0, stream>>>(Ocb, wob, (float*)d_out);
}

// Round 2
// 205.655 us; speedup vs baseline: 2.3920x; 2.3920x over previous
//
#include <hip/hip_runtime.h>

typedef unsigned short u16;
typedef u16 u16x8 __attribute__((ext_vector_type(8)));
typedef u16 u16x4 __attribute__((ext_vector_type(4)));
typedef float f32x4 __attribute__((ext_vector_type(4)));
typedef __bf16 bf16x8 __attribute__((ext_vector_type(8)));

#define SCALE_QK 0.35355339059327373f   /* 64^-0.25 */
#define LAMBDA_INIT 0.7836057665316245f
#define ONE_MINUS_LI 0.21639423346837554f

__device__ __forceinline__ u16 f2bf(float f) {
  unsigned u = __builtin_bit_cast(unsigned, f);
  u = (u + 0x7FFFu + ((u >> 16) & 1u)) >> 16;   // RNE
  return (u16)u;
}
__device__ __forceinline__ float bf2f(u16 h) {
  unsigned u = ((unsigned)h) << 16;
  return __builtin_bit_cast(float, u);
}
__device__ __forceinline__ f32x4 mfma16(bf16x8 a, bf16x8 b, f32x4 c) {
  return __builtin_amdgcn_mfma_f32_16x16x32_bf16(a, b, c, 0, 0, 0);
}
// async global->LDS, 16B per lane; LDS dest = wave-uniform base + lane*16
__device__ __forceinline__ void gld16(const void* g, void* l) {
  __builtin_amdgcn_global_load_lds(
      (const __attribute__((address_space(1))) unsigned int*)g,
      (__attribute__((address_space(3))) unsigned int*)l, 16, 0, 0);
}

// ---------------- fp32 -> bf16 convert ----------------
__global__ void cvt_f32_bf16_kernel(const float* __restrict__ in, u16* __restrict__ out, int n4) {
  int idx = blockIdx.x * blockDim.x + threadIdx.x;
  if (idx >= n4) return;
  f32x4 v = *(const f32x4*)(in + (size_t)idx * 4);
  u16x4 o;
  o[0] = f2bf(v[0]); o[1] = f2bf(v[1]); o[2] = f2bf(v[2]); o[3] = f2bf(v[3]);
  *(u16x4*)(out + (size_t)idx * 4) = o;
}

// ---------------- RoPE cos/sin table: [s=2048][i=32] ----------------
__global__ void rope_table_kernel(float* __restrict__ cosT, float* __restrict__ sinT) {
  int idx = blockIdx.x * blockDim.x + threadIdx.x;
  if (idx >= 2048 * 32) return;
  int i = idx & 31;
  int t = idx >> 5;
  float invf = expf(-(float)i * 0.2878231366242558f);
  float f = (float)t * invf;
  cosT[idx] = cosf(f);
  sinT[idx] = sinf(f);
}

// ---------------- lambda scalar ----------------
__global__ void lam_kernel(const float* __restrict__ lq1, const float* __restrict__ lk1,
                           const float* __restrict__ lq2, const float* __restrict__ lk2,
                           float* __restrict__ out) {
  int l = threadIdx.x & 63;
  float a = lq1[l] * lk1[l];
  float b = lq2[l] * lk2[l];
#pragma unroll
  for (int m = 1; m < 64; m <<= 1) {
    a += __shfl_xor(a, m);
    b += __shfl_xor(b, m);
  }
  if (l == 0) out[0] = expf(a) - expf(b) + LAMBDA_INIT;
}

// ---------------- GEMM C = A @ B^T (A[M][K], B[N][K], bf16 in) ----------------
template<bool F32OUT>
__device__ __forceinline__ void gemm_body(const u16* __restrict__ A, const u16* __restrict__ Bm,
                                          void* __restrict__ C, int M, int N, int K) {
  __shared__ __align__(16) u16 As[128][72];
  __shared__ __align__(16) u16 Bs[128][72];
  const int tid = threadIdx.x;
  const int lane = tid & 63, wid = tid >> 6;
  const int wr = wid >> 1, wc = wid & 1;
  const int c = lane & 15, g = lane >> 4;
  const int bm = blockIdx.x * 128, bn = blockIdx.y * 128;
  const int lrow = tid >> 3;          // 0..31
  const int lcol = (tid & 7) * 8;     // 0..56
  f32x4 acc[4][4];
#pragma unroll
  for (int m = 0; m < 4; ++m)
#pragma unroll
    for (int n = 0; n < 4; ++n) acc[m][n] = (f32x4){0.f, 0.f, 0.f, 0.f};

  for (int k0 = 0; k0 < K; k0 += 64) {
#pragma unroll
    for (int i = 0; i < 4; ++i) {
      int r = lrow + i * 32;
      *(u16x8*)(&As[r][lcol]) = *(const u16x8*)(A + (size_t)(bm + r) * K + k0 + lcol);
      *(u16x8*)(&Bs[r][lcol]) = *(const u16x8*)(Bm + (size_t)(bn + r) * K + k0 + lcol);
    }
    __syncthreads();
#pragma unroll
    for (int kk = 0; kk < 2; ++kk) {
      const int co = kk * 32 + g * 8;
      bf16x8 af[4], bfm[4];
#pragma unroll
      for (int m = 0; m < 4; ++m)
        af[m] = __builtin_bit_cast(bf16x8, *(const u16x8*)(&As[wr * 64 + m * 16 + c][co]));
#pragma unroll
      for (int n = 0; n < 4; ++n)
        bfm[n] = __builtin_bit_cast(bf16x8, *(const u16x8*)(&Bs[wc * 64 + n * 16 + c][co]));
#pragma unroll
      for (int m = 0; m < 4; ++m)
#pragma unroll
        for (int n = 0; n < 4; ++n)
          acc[m][n] = mfma16(af[m], bfm[n], acc[m][n]);
    }
    __syncthreads();
  }
#pragma unroll
  for (int m = 0; m < 4; ++m)
#pragma unroll
    for (int n = 0; n < 4; ++n) {
      const int col = bn + wc * 64 + n * 16 + c;
      const int row0 = bm + wr * 64 + m * 16 + g * 4;
#pragma unroll
      for (int r = 0; r < 4; ++r) {
        if constexpr (F32OUT) ((float*)C)[(size_t)(row0 + r) * N + col] = acc[m][n][r];
        else ((u16*)C)[(size_t)(row0 + r) * N + col] = f2bf(acc[m][n][r]);
      }
    }
}

__global__ __launch_bounds__(256) void gemm_qkv_kernel(
    const u16* __restrict__ A,
    const u16* __restrict__ B0, const u16* __restrict__ B1, const u16* __restrict__ B2,
    u16* __restrict__ C0, u16* __restrict__ C1, u16* __restrict__ C2) {
  const u16* Bm = (blockIdx.z == 0) ? B0 : (blockIdx.z == 1) ? B1 : B2;
  u16* C = (blockIdx.z == 0) ? C0 : (blockIdx.z == 1) ? C1 : C2;
  gemm_body<false>(A, Bm, C, 4096, 1024, 1024);
}

__global__ __launch_bounds__(256) void gemm_f32_kernel(const u16* __restrict__ A,
                                                       const u16* __restrict__ Bm,
                                                       float* __restrict__ C) {
  gemm_body<true>(A, Bm, C, 4096, 1024, 1024);
}

// ---------------- RoPE in-place on [b][s][16][64] bf16 ----------------
__global__ void rope_kernel(u16* __restrict__ X, const float* __restrict__ cosT,
                            const float* __restrict__ sinT) {
  int idx = blockIdx.x * blockDim.x + threadIdx.x;
  if (idx >= 2 * 2048 * 16 * 8) return;
  int seg = idx & 7;
  int head2 = (idx >> 3) & 15;
  int s = (idx >> 7) & 2047;
  int b = idx >> 18;
  size_t base = (((size_t)(b * 2048 + s)) * 16 + head2) * 64 + seg * 8;
  u16x8 v = *(const u16x8*)(X + base);
  u16x8 o;
#pragma unroll
  for (int j = 0; j < 4; ++j) {
    int i = seg * 4 + j;
    float cc = cosT[s * 32 + i];
    float sn = sinT[s * 32 + i];
    float xe = bf2f(v[2 * j]);
    float xo = bf2f(v[2 * j + 1]);
    o[2 * j]     = f2bf(xe * cc - xo * sn);
    o[2 * j + 1] = f2bf(xo * cc + xe * sn);
  }
  *(u16x8*)(X + base) = o;
}

// ---------------- V transpose: [b][s][h*128+d] -> Vt[(b*8+h)*128+d][s] ----------------
__global__ __launch_bounds__(256) void transpose_v_kernel(const u16* __restrict__ V,
                                                          u16* __restrict__ Vt) {
  __shared__ __align__(16) u16 tile[64][136];
  const int s0 = blockIdx.x * 64;
  const int bh = blockIdx.y;           // b*8 + h
  const int b = bh >> 3, h = bh & 7;
  const int t = threadIdx.x;
  {
    const int dseg = (t & 15) * 8;
    const int sl = t >> 4;             // 0..15
#pragma unroll
    for (int it = 0; it < 4; ++it) {
      int srow = sl + it * 16;
      u16x8 v = *(const u16x8*)(V + (size_t)((b * 2048) + s0 + srow) * 1024 + h * 128 + dseg);
      *(u16x8*)(&tile[srow][dseg]) = v;
    }
  }
  __syncthreads();
  {
    const int sseg = (t & 7) * 8;
    const int dl = t >> 3;             // 0..31
#pragma unroll
    for (int it = 0; it < 4; ++it) {
      int d = dl + it * 32;
      u16x8 o;
#pragma unroll
      for (int r = 0; r < 8; ++r) o[r] = tile[sseg + r][d];
      *(u16x8*)(Vt + ((size_t)bh * 128 + d) * 2048 + s0 + sseg) = o;
    }
  }
}

// ---------------- fused flash diff-attention (v2) ----------------
// 512 threads = 8 waves. Waves 0-3: path 0, waves 4-7: path 1; wave sw owns 16 q rows.
// K (both paths) + V staged in LDS per 64-key tile via global_load_lds with
// pre-swizzled source (col16 ^= row&7) for conflict-free ds_read_b128.
// Grid: 512 blocks 1D, XCD-chunked decode so one bh's 32 q-tiles share an XCD L2.
__global__ __launch_bounds__(512, 4) void attn_kernel(
    const u16* __restrict__ Qb, const u16* __restrict__ Kb, const u16* __restrict__ Vt,
    const float* __restrict__ lamp, const float* __restrict__ lnw, const float* __restrict__ lnb,
    u16* __restrict__ Oc) {
  __shared__ __align__(16) char smem[51200];
  u16 (*Ks)[64][64]  = (u16 (*)[64][64])smem;            // [2][64][64]  16KB
  u16 (*Vs)[64]      = (u16 (*)[64])(smem + 16384);      // [128][64]    16KB
  u16 (*plds)[16][72]= (u16 (*)[16][72])(smem + 32768);  // [8][16][72]  18KB

  const int tid = threadIdx.x;
  const int lane = tid & 63;
  const int wid = tid >> 6;            // 0..7
  const int c = lane & 15;
  const int g = lane >> 4;
  const int lrow8 = lane >> 3;         // 0..7
  const int c16 = lane & 7;

  const int B = blockIdx.x;
  const int xcd = B & 7, idx = B >> 3;
  const int bh = xcd * 2 + (idx >> 5); // 0..15
  const int qt = idx & 31;             // 0..31
  const int b = bh >> 3, h = bh & 7;
  const int p = wid >> 2, sw = wid & 3;
  const int head2 = 2 * h + p;

  const u16* qbase = Qb + ((size_t)((b * 2048) + qt * 64 + sw * 16 + c) * 16 + head2) * 64 + g * 8;
  bf16x8 qf0 = __builtin_bit_cast(bf16x8, *(const u16x8*)(qbase));
  bf16x8 qf1 = __builtin_bit_cast(bf16x8, *(const u16x8*)(qbase + 32));

  f32x4 acc[8];
#pragma unroll
  for (int i = 0; i < 8; ++i) acc[i] = (f32x4){0.f, 0.f, 0.f, 0.f};
  float mrow[4] = {-1e30f, -1e30f, -1e30f, -1e30f};
  float Lrow[4] = {0.f, 0.f, 0.f, 0.f};

  for (int k0 = 0; k0 < 2048; k0 += 64) {
    // ---- cooperative stage: K0,K1 (8KB each), V (16KB); 1KB per wave-call ----
#pragma unroll
    for (int j = 0; j < 4; ++j) {
      const int cid = (wid << 2) | j;       // 0..31, wave-uniform
      if (cid < 16) {
        const int pp = cid >> 3;
        const int row = ((cid & 7) << 3) + lrow8;       // key row 0..63
        const int cs = c16 ^ (row & 7);
        gld16(Kb + ((size_t)(b * 2048 + k0 + row) * 16 + 2 * h + pp) * 64 + cs * 8,
              &Ks[pp][(cid & 7) << 3][0]);
      } else {
        const int row = ((cid & 15) << 3) + lrow8;      // d row 0..127
        const int cs = c16 ^ (row & 7);
        gld16(Vt + ((size_t)(bh * 128 + row)) * 2048 + k0 + cs * 8,
              &Vs[(cid & 15) << 3][0]);
      }
    }
    __syncthreads();

    // ---- QK^T from LDS (swizzled reads) ----
    f32x4 sacc[4];
#pragma unroll
    for (int n = 0; n < 4; ++n) sacc[n] = (f32x4){0.f, 0.f, 0.f, 0.f};
#pragma unroll
    for (int n = 0; n < 4; ++n) {
      const int kr = n * 16 + c;
      bf16x8 kf0 = __builtin_bit_cast(bf16x8, *(const u16x8*)(&Ks[p][kr][(g ^ (c & 7)) << 3]));
      bf16x8 kf1 = __builtin_bit_cast(bf16x8, *(const u16x8*)(&Ks[p][kr][((4 + g) ^ (c & 7)) << 3]));
      sacc[n] = mfma16(qf0, kf0, sacc[n]);
      sacc[n] = mfma16(qf1, kf1, sacc[n]);
    }

    // ---- online softmax (identical numerics to v1) ----
    float pv[4][4];
    float alpha[4];
#pragma unroll
    for (int r = 0; r < 4; ++r) {
      float s0 = sacc[0][r] * SCALE_QK, s1 = sacc[1][r] * SCALE_QK;
      float s2 = sacc[2][r] * SCALE_QK, s3 = sacc[3][r] * SCALE_QK;
      float mx = fmaxf(fmaxf(s0, s1), fmaxf(s2, s3));
      mx = fmaxf(mx, __shfl_xor(mx, 1));
      mx = fmaxf(mx, __shfl_xor(mx, 2));
      mx = fmaxf(mx, __shfl_xor(mx, 4));
      mx = fmaxf(mx, __shfl_xor(mx, 8));
      float mnew = fmaxf(mrow[r], mx);
      float al = __expf(mrow[r] - mnew);
      float p0 = __expf(s0 - mnew), p1 = __expf(s1 - mnew);
      float p2 = __expf(s2 - mnew), p3 = __expf(s3 - mnew);
      pv[0][r] = p0; pv[1][r] = p1; pv[2][r] = p2; pv[3][r] = p3;
      float sum = p0 + p1 + p2 + p3;
      sum += __shfl_xor(sum, 1);
      sum += __shfl_xor(sum, 2);
      sum += __shfl_xor(sum, 4);
      sum += __shfl_xor(sum, 8);
      Lrow[r] = Lrow[r] * al + sum;
      mrow[r] = mnew;
      alpha[r] = al;
    }
#pragma unroll
    for (int i = 0; i < 8; ++i) {
#pragma unroll
      for (int r = 0; r < 4; ++r) acc[i][r] *= alpha[r];
    }

    // ---- P via wave-private LDS (in-order DS pipe, no barrier needed) ----
#pragma unroll
    for (int n = 0; n < 4; ++n)
#pragma unroll
      for (int r = 0; r < 4; ++r)
        plds[wid][g * 4 + r][n * 16 + c] = f2bf(pv[n][r]);

    // ---- PV from LDS V (swizzled reads) ----
#pragma unroll
    for (int ks = 0; ks < 2; ++ks) {
      bf16x8 pf = __builtin_bit_cast(bf16x8, *(const u16x8*)(&plds[wid][c][ks * 32 + g * 8]));
#pragma unroll
      for (int nO = 0; nO < 8; ++nO) {
        bf16x8 vf = __builtin_bit_cast(bf16x8,
            *(const u16x8*)(&Vs[nO * 16 + c][(((ks << 2) | g) ^ (c & 7)) << 3]));
        acc[nO] = mfma16(pf, vf, acc[nO]);
      }
    }
    __syncthreads();
  }

  // ---- cross-path combine + RMS norm epilogue ----
  float* comb = (float*)smem;   // [4][16][132] f32, reuses tile LDS
  const float lam = lamp[0];
  if (wid >= 4) {
#pragma unroll
    for (int r = 0; r < 4; ++r) {
      float inv2 = 1.f / Lrow[r];
#pragma unroll
      for (int nO = 0; nO < 8; ++nO)
        comb[((wid - 4) * 16 + g * 4 + r) * 132 + nO * 16 + c] = acc[nO][r] * inv2;
    }
  }
  __syncthreads();
  if (wid < 4) {
    float lw[8], lb[8];
#pragma unroll
    for (int nO = 0; nO < 8; ++nO) {
      lw[nO] = lnw[nO * 16 + c];
      lb[nO] = lnb[nO * 16 + c];
    }
#pragma unroll
    for (int r = 0; r < 4; ++r) {
      float inv1 = 1.f / Lrow[r];
      float vals[8];
      float ss = 0.f;
#pragma unroll
      for (int nO = 0; nO < 8; ++nO) {
        float o2 = comb[(wid * 16 + g * 4 + r) * 132 + nO * 16 + c];
        float v = acc[nO][r] * inv1 - lam * o2;
        vals[nO] = v;
        ss += v * v;
      }
      ss += __shfl_xor(ss, 1);
      ss += __shfl_xor(ss, 2);
      ss += __shfl_xor(ss, 4);
      ss += __shfl_xor(ss, 8);
      float rinv = rsqrtf(ss * (1.0f / 128.0f) + 1e-8f);
      int srow = b * 2048 + qt * 64 + wid * 16 + g * 4 + r;
#pragma unroll
      for (int nO = 0; nO < 8; ++nO) {
        float v = (vals[nO] * rinv * lw[nO] + lb[nO]) * ONE_MINUS_LI;
        Oc[(size_t)srow * 1024 + h * 128 + nO * 16 + c] = f2bf(v);
      }
    }
  }
}

extern "C" void kernel_launch(void* const* d_in, const int* in_sizes, int n_in,
                              void* d_out, int out_size, void* d_ws, size_t ws_size,
                              hipStream_t stream) {
  const float* x   = (const float*)d_in[0];
  const float* Wq  = (const float*)d_in[1];
  const float* Wk  = (const float*)d_in[2];
  const float* Wv  = (const float*)d_in[3];
  const float* Wo  = (const float*)d_in[4];
  const float* lq1 = (const float*)d_in[5];
  const float* lk1 = (const float*)d_in[6];
  const float* lq2 = (const float*)d_in[7];
  const float* lk2 = (const float*)d_in[8];
  const float* lnw = (const float*)d_in[9];
  const float* lnb = (const float*)d_in[10];

  char* w = (char*)d_ws;
  size_t off = 0;
  auto alloc = [&](size_t bytes) {
    char* p = w + off;
    off = (off + bytes + 255) & ~(size_t)255;
    return p;
  };
  u16* xb   = (u16*)alloc(4096ull * 1024 * 2);
  u16* wqb  = (u16*)alloc(1024ull * 1024 * 2);
  u16* wkb  = (u16*)alloc(1024ull * 1024 * 2);
  u16* wvb  = (u16*)alloc(1024ull * 1024 * 2);
  u16* wob  = (u16*)alloc(1024ull * 1024 * 2);
  u16* Qb   = (u16*)alloc(4096ull * 1024 * 2);
  u16* Kb   = (u16*)alloc(4096ull * 1024 * 2);
  u16* Vb   = (u16*)alloc(4096ull * 1024 * 2);
  u16* Vt   = (u16*)alloc(4096ull * 1024 * 2);
  u16* Ocb  = (u16*)alloc(4096ull * 1024 * 2);
  float* cosT = (float*)alloc(2048ull * 32 * 4);
  float* sinT = (float*)alloc(2048ull * 32 * 4);
  float* lamp = (float*)alloc(256);

  // converts
  cvt_f32_bf16_kernel<<<4096, 256, 0, stream>>>(x, xb, 4096 * 1024 / 4);
  cvt_f32_bf16_kernel<<<1024, 256, 0, stream>>>(Wq, wqb, 1024 * 1024 / 4);
  cvt_f32_bf16_kernel<<<1024, 256, 0, stream>>>(Wk, wkb, 1024 * 1024 / 4);
  cvt_f32_bf16_kernel<<<1024, 256, 0, stream>>>(Wv, wvb, 1024 * 1024 / 4);
  cvt_f32_bf16_kernel<<<1024, 256, 0, stream>>>(Wo, wob, 1024 * 1024 / 4);
  rope_table_kernel<<<256, 256, 0, stream>>>(cosT, sinT);
  lam_kernel<<<1, 64, 0, stream>>>(lq1, lk1, lq2, lk2, lamp);

  // QKV projections (fused via grid.z)
  gemm_qkv_kernel<<<dim3(32, 8, 3), 256, 0, stream>>>(xb, wqb, wkb, wvb, Qb, Kb, Vb);

  // RoPE on Q and K
  rope_kernel<<<2048, 256, 0, stream>>>(Qb, cosT, sinT);
  rope_kernel<<<2048, 256, 0, stream>>>(Kb, cosT, sinT);

  // V transpose for PV fragment layout
  transpose_v_kernel<<<dim3(32, 16), 256, 0, stream>>>(Vb, Vt);

  // fused diff flash attention + RMS norm (8-wave, LDS-staged K/V)
  attn_kernel<<<512, 512, 0, stream>>>(Qb, Kb, Vt, lamp, lnw, lnb, Ocb);

  // output projection
  gemm_f32_kernel<<<dim3(32, 8), 256, 0, stream>>>(Ocb, wob, (float*)d_out);
}

// Round 3
// 179.049 us; speedup vs baseline: 2.7474x; 1.1486x over previous
//
#include <hip/hip_runtime.h>

typedef unsigned short u16;
typedef u16 u16x8 __attribute__((ext_vector_type(8)));
typedef u16 u16x4 __attribute__((ext_vector_type(4)));
typedef float f32x4 __attribute__((ext_vector_type(4)));
typedef __bf16 bf16x8 __attribute__((ext_vector_type(8)));

#define SCALE_L2E 0.51006972864f  /* 64^-0.25 * log2(e) */
#define LAMBDA_INIT 0.7836057665316245f
#define ONE_MINUS_LI 0.21639423346837554f
#define DEFER_THR 11.0f           /* log2 units; P <= 2^11 */

__device__ __forceinline__ u16 b16(float f) {
  return __builtin_bit_cast(u16, (__bf16)f);
}
__device__ __forceinline__ float bf2f(u16 h) {
  unsigned u = ((unsigned)h) << 16;
  return __builtin_bit_cast(float, u);
}
__device__ __forceinline__ f32x4 mfma16(bf16x8 a, bf16x8 b, f32x4 c) {
  return __builtin_amdgcn_mfma_f32_16x16x32_bf16(a, b, c, 0, 0, 0);
}
// async global->LDS, 16B/lane; LDS dest = wave-uniform base + lane*16
__device__ __forceinline__ void gld16(const void* g, void* l) {
  __builtin_amdgcn_global_load_lds(
      (const __attribute__((address_space(1))) unsigned int*)g,
      (__attribute__((address_space(3))) unsigned int*)l, 16, 0, 0);
}

// ---------------- fused prep: f32->bf16 converts + RoPE table + lambda ----------------
__global__ void prep_kernel(const float* __restrict__ x, const float* __restrict__ Wq,
                            const float* __restrict__ Wk, const float* __restrict__ Wv,
                            const float* __restrict__ Wo,
                            const float* __restrict__ lq1, const float* __restrict__ lk1,
                            const float* __restrict__ lq2, const float* __restrict__ lk2,
                            u16* __restrict__ xb, u16* __restrict__ wqb, u16* __restrict__ wkb,
                            u16* __restrict__ wvb, u16* __restrict__ wob,
                            float* __restrict__ cosT, float* __restrict__ sinT,
                            float* __restrict__ lamp) {
  const int bid = blockIdx.x, tid = threadIdx.x;
  if (bid < 8192) {
    const float* src; u16* dst; int off;
    if (bid < 4096) { src = x; dst = xb; off = bid; }
    else {
      const int wsel = (bid - 4096) >> 10;
      off = (bid - 4096) & 1023;
      src = wsel == 0 ? Wq : wsel == 1 ? Wk : wsel == 2 ? Wv : Wo;
      dst = wsel == 0 ? wqb : wsel == 1 ? wkb : wsel == 2 ? wvb : wob;
    }
    const size_t i = (size_t)off * 256 + tid;
    f32x4 v = *(const f32x4*)(src + i * 4);
    u16x4 o;
    o[0] = b16(v[0]); o[1] = b16(v[1]); o[2] = b16(v[2]); o[3] = b16(v[3]);
    *(u16x4*)(dst + i * 4) = o;
  } else if (bid < 8448) {
    const int i = (bid - 8192) * 256 + tid;   // 0..65535 = [s=2048][fi=32]
    const int fi = i & 31, t = i >> 5;
    float invf = expf(-(float)fi * 0.2878231366242558f);
    float f = (float)t * invf;
    cosT[i] = cosf(f);
    sinT[i] = sinf(f);
  } else if (tid < 64) {
    int l = tid;
    float a = lq1[l] * lk1[l];
    float bb = lq2[l] * lk2[l];
#pragma unroll
    for (int m = 1; m < 64; m <<= 1) {
      a += __shfl_xor(a, m);
      bb += __shfl_xor(bb, m);
    }
    if (l == 0) lamp[0] = expf(a) - expf(bb) + LAMBDA_INIT;
  }
}

// ---------------- GEMM C = A @ B^T via global_load_lds + XOR swizzle ----------------
template<bool F32OUT>
__device__ __forceinline__ void gemm_body(const u16* __restrict__ A, const u16* __restrict__ Bm,
                                          void* __restrict__ C, int M, int N, int K) {
  __shared__ __align__(1024) u16 As[128][64];
  __shared__ __align__(1024) u16 Bs[128][64];
  const int tid = threadIdx.x;
  const int lane = tid & 63, wid = tid >> 6;
  const int wr = wid >> 1, wc = wid & 1;
  const int c = lane & 15, g = lane >> 4;
  const int bm = blockIdx.x * 128, bn = blockIdx.y * 128;
  const int srow = lane >> 3;          // 0..7 (row within 8-row chunk)
  const int scol = lane & 7;
  f32x4 acc[4][4];
#pragma unroll
  for (int m = 0; m < 4; ++m)
#pragma unroll
    for (int n = 0; n < 4; ++n) acc[m][n] = (f32x4){0.f, 0.f, 0.f, 0.f};

  for (int k0 = 0; k0 < K; k0 += 64) {
#pragma unroll
    for (int j = 0; j < 8; ++j) {
      const int cid = (wid << 3) | j;       // 0..31, wave-uniform chunk id
      if (cid < 16) {
        const int row = (cid << 3) + srow;
        gld16(A + (size_t)(bm + row) * K + k0 + ((scol ^ srow) << 3), &As[cid << 3][0]);
      } else {
        const int ch = cid - 16;
        const int row = (ch << 3) + srow;
        gld16(Bm + (size_t)(bn + row) * K + k0 + ((scol ^ srow) << 3), &Bs[ch << 3][0]);
      }
    }
    __syncthreads();
#pragma unroll
    for (int kk = 0; kk < 2; ++kk) {
      bf16x8 af[4], bfm[4];
#pragma unroll
      for (int m = 0; m < 4; ++m)
        af[m] = __builtin_bit_cast(bf16x8,
            *(const u16x8*)(&As[wr * 64 + m * 16 + c][(((kk << 2) | g) ^ (c & 7)) << 3]));
#pragma unroll
      for (int n = 0; n < 4; ++n)
        bfm[n] = __builtin_bit_cast(bf16x8,
            *(const u16x8*)(&Bs[wc * 64 + n * 16 + c][(((kk << 2) | g) ^ (c & 7)) << 3]));
#pragma unroll
      for (int m = 0; m < 4; ++m)
#pragma unroll
        for (int n = 0; n < 4; ++n)
          acc[m][n] = mfma16(af[m], bfm[n], acc[m][n]);
    }
    __syncthreads();
  }
#pragma unroll
  for (int m = 0; m < 4; ++m)
#pragma unroll
    for (int n = 0; n < 4; ++n) {
      const int col = bn + wc * 64 + n * 16 + c;
      const int row0 = bm + wr * 64 + m * 16 + g * 4;
#pragma unroll
      for (int r = 0; r < 4; ++r) {
        if constexpr (F32OUT) ((float*)C)[(size_t)(row0 + r) * N + col] = acc[m][n][r];
        else ((u16*)C)[(size_t)(row0 + r) * N + col] = b16(acc[m][n][r]);
      }
    }
}

__global__ __launch_bounds__(256) void gemm_qkv_kernel(
    const u16* __restrict__ A,
    const u16* __restrict__ B0, const u16* __restrict__ B1, const u16* __restrict__ B2,
    u16* __restrict__ C0, u16* __restrict__ C1, u16* __restrict__ C2) {
  const u16* Bm = (blockIdx.z == 0) ? B0 : (blockIdx.z == 1) ? B1 : B2;
  u16* C = (blockIdx.z == 0) ? C0 : (blockIdx.z == 1) ? C1 : C2;
  gemm_body<false>(A, Bm, C, 4096, 1024, 1024);
}

__global__ __launch_bounds__(256) void gemm_f32_kernel(const u16* __restrict__ A,
                                                       const u16* __restrict__ Bm,
                                                       float* __restrict__ C) {
  gemm_body<true>(A, Bm, C, 4096, 1024, 1024);
}

// ---------------- RoPE in-place on Q and K: [b][s][16][64] bf16 ----------------
__global__ void rope_kernel(u16* __restrict__ Q, u16* __restrict__ K,
                            const float* __restrict__ cosT, const float* __restrict__ sinT) {
  int gid = blockIdx.x * blockDim.x + threadIdx.x;   // 0..1048575
  u16* X = (gid < 524288) ? Q : K;
  int idx = gid & 524287;
  int seg = idx & 7;
  int head2 = (idx >> 3) & 15;
  int s = (idx >> 7) & 2047;
  int b = idx >> 18;
  size_t base = (((size_t)(b * 2048 + s)) * 16 + head2) * 64 + seg * 8;
  u16x8 v = *(const u16x8*)(X + base);
  u16x8 o;
#pragma unroll
  for (int j = 0; j < 4; ++j) {
    int i = seg * 4 + j;
    float cc = cosT[s * 32 + i];
    float sn = sinT[s * 32 + i];
    float xe = bf2f(v[2 * j]);
    float xo = bf2f(v[2 * j + 1]);
    o[2 * j]     = b16(xe * cc - xo * sn);
    o[2 * j + 1] = b16(xo * cc + xe * sn);
  }
  *(u16x8*)(X + base) = o;
}

// ---------------- V transpose: [b][s][h*128+d] -> Vt[(b*8+h)*128+d][s] ----------------
__global__ __launch_bounds__(256) void transpose_v_kernel(const u16* __restrict__ V,
                                                          u16* __restrict__ Vt) {
  __shared__ __align__(16) u16 tile[64][136];
  const int s0 = blockIdx.x * 64;
  const int bh = blockIdx.y;
  const int b = bh >> 3, h = bh & 7;
  const int t = threadIdx.x;
  {
    const int dseg = (t & 15) * 8;
    const int sl = t >> 4;
#pragma unroll
    for (int it = 0; it < 4; ++it) {
      int srow = sl + it * 16;
      u16x8 v = *(const u16x8*)(V + (size_t)((b * 2048) + s0 + srow) * 1024 + h * 128 + dseg);
      *(u16x8*)(&tile[srow][dseg]) = v;
    }
  }
  __syncthreads();
  {
    const int sseg = (t & 7) * 8;
    const int dl = t >> 3;
#pragma unroll
    for (int it = 0; it < 4; ++it) {
      int d = dl + it * 32;
      u16x8 o;
#pragma unroll
      for (int r = 0; r < 8; ++r) o[r] = tile[sseg + r][d];
      *(u16x8*)(Vt + ((size_t)bh * 128 + d) * 2048 + s0 + sseg) = o;
    }
  }
}

// ---------------- fused flash diff-attention (v3) ----------------
// 256 thr = 4 waves: wave = (path p = wid>>1, row-subgroup sg = wid&1), 32 q-rows/wave.
// Swapped QK^T (mfma(K,Q)): per-lane q-row = c, lane-local P row. KVBLK=32,
// double-buffered K/V staging via global_load_lds (XOR-swizzled source),
// one barrier per tile. Defer-max (log2 domain, THR=11). Diff+RMS in epilogue.
__global__ __launch_bounds__(256, 2) void attn_kernel(
    const u16* __restrict__ Qb, const u16* __restrict__ Kb, const u16* __restrict__ Vt,
    const float* __restrict__ lamp, const float* __restrict__ lnw, const float* __restrict__ lnb,
    u16* __restrict__ Oc) {
  // buf t&1 at smem + (t&1)*16384: K[2][32][64] (8KB) + V[128][32] (8KB)
  // P: smem + 32768 + wid*1280  ([16][40] u16 per wave)
  __shared__ __align__(1024) char smem[38912];
  const int tid = threadIdx.x;
  const int lane = tid & 63;
  const int wid = tid >> 6;            // 0..3
  const int c = lane & 15, g = lane >> 4;
  const int p = wid >> 1, sg = wid & 1;

  const int B = blockIdx.x;
  const int xcd = B & 7, bidx = B >> 3;
  const int bh = xcd * 2 + (bidx >> 5);
  const int qt = bidx & 31;
  const int b = bh >> 3, h = bh & 7;
  const int head2 = 2 * h + p;

  // Q fragments for 2 row-groups (row = qt*64 + sg*32 + rg*16 + c)
  bf16x8 qf[2][2];
#pragma unroll
  for (int rg = 0; rg < 2; ++rg) {
    const int row = qt * 64 + sg * 32 + rg * 16 + c;
    const u16* qb_ = Qb + ((size_t)(b * 2048 + row) * 16 + head2) * 64 + g * 8;
    qf[rg][0] = __builtin_bit_cast(bf16x8, *(const u16x8*)(qb_));
    qf[rg][1] = __builtin_bit_cast(bf16x8, *(const u16x8*)(qb_ + 32));
  }

  f32x4 acc[2][8];
#pragma unroll
  for (int rg = 0; rg < 2; ++rg)
#pragma unroll
    for (int i = 0; i < 8; ++i) acc[rg][i] = (f32x4){0.f, 0.f, 0.f, 0.f};
  float m_r[2] = {-3.0e38f, -3.0e38f};
  float L_r[2] = {0.f, 0.f};

  u16* Pw = (u16*)(smem + 32768 + wid * 1280);
  char* Pwb = (char*)Pw;

  auto STAGE = [&](char* dst, int k0) {
#pragma unroll
    for (int j = 0; j < 4; ++j) {
      const int cid = (wid << 2) | j;     // 0..15, wave-uniform
      if (cid < 8) {
        const int pp = cid >> 2;          // path
        const int ch = cid & 3;           // 8-row chunk (128B rows)
        const int krow = (ch << 3) + (lane >> 3);
        gld16(Kb + ((size_t)(b * 2048 + k0 + krow) * 16 + 2 * h + pp) * 64 +
                  (((lane & 7) ^ (krow & 7)) << 3),
              dst + pp * 4096 + ch * 1024);
      } else {
        const int ch = cid & 7;           // 16-row chunk (64B rows)
        const int vrow = (ch << 4) + (lane >> 2);
        gld16(Vt + ((size_t)(bh * 128 + vrow)) * 2048 + k0 +
                  (((lane & 3) ^ (vrow & 3)) << 3),
              dst + 8192 + ch * 1024);
      }
    }
  };

  STAGE(smem, 0);
  __syncthreads();

  for (int t = 0; t < 64; ++t) {
    char* bb = smem + (t & 1) * 16384;
    if (t < 63) STAGE(smem + ((t + 1) & 1) * 16384, (t + 1) * 32);

    // K fragments (both halves of d), shared across both row-groups
    bf16x8 kf[2][2];
#pragma unroll
    for (int n = 0; n < 2; ++n)
#pragma unroll
      for (int hf = 0; hf < 2; ++hf)
        kf[n][hf] = __builtin_bit_cast(bf16x8,
            *(const u16x8*)(bb + p * 4096 + (n * 16 + c) * 128 +
                            ((((hf << 2) | g) ^ (c & 7)) << 4)));

    bf16x8 pf[2];
#pragma unroll
    for (int rg = 0; rg < 2; ++rg) {
      f32x4 sacc[2];
      sacc[0] = (f32x4){0.f, 0.f, 0.f, 0.f};
      sacc[1] = (f32x4){0.f, 0.f, 0.f, 0.f};
#pragma unroll
      for (int n = 0; n < 2; ++n) {
        sacc[n] = mfma16(kf[n][0], qf[rg][0], sacc[n]);   // swapped: A=K, B=Q
        sacc[n] = mfma16(kf[n][1], qf[rg][1], sacc[n]);
      }
      // lane holds S^T[key = n*16+g*4+r][q-row = c], log2 domain
      float sl[8];
#pragma unroll
      for (int n = 0; n < 2; ++n)
#pragma unroll
        for (int r = 0; r < 4; ++r) sl[n * 4 + r] = sacc[n][r] * SCALE_L2E;
      float mx = sl[0];
#pragma unroll
      for (int i = 1; i < 8; ++i) mx = fmaxf(mx, sl[i]);
      mx = fmaxf(mx, __shfl_xor(mx, 16));
      mx = fmaxf(mx, __shfl_xor(mx, 32));
      if (!__all(mx - m_r[rg] <= DEFER_THR)) {
        float mnew = fmaxf(m_r[rg], mx);
        float al = __builtin_amdgcn_exp2f(m_r[rg] - mnew);
        m_r[rg] = mnew;
        L_r[rg] *= al;
#pragma unroll
        for (int r = 0; r < 4; ++r) {
          float a2 = __shfl(al, g * 4 + r);
#pragma unroll
          for (int nO = 0; nO < 8; ++nO) acc[rg][nO][r] *= a2;
        }
      }
      float pe[8];
      float sm = 0.f;
#pragma unroll
      for (int i = 0; i < 8; ++i) {
        pe[i] = __builtin_amdgcn_exp2f(sl[i] - m_r[rg]);
        sm += pe[i];
      }
      sm += __shfl_xor(sm, 16);
      sm += __shfl_xor(sm, 32);
      L_r[rg] += sm;
      // P pack -> LDS (row c, keys n*16+4g..+3), then A-fragment read
#pragma unroll
      for (int n = 0; n < 2; ++n) {
        u16x4 pw;
        pw[0] = b16(pe[n * 4 + 0]); pw[1] = b16(pe[n * 4 + 1]);
        pw[2] = b16(pe[n * 4 + 2]); pw[3] = b16(pe[n * 4 + 3]);
        *(u16x4*)(Pwb + c * 80 + n * 32 + g * 8) = pw;
      }
      pf[rg] = __builtin_bit_cast(bf16x8, *(const u16x8*)(Pwb + c * 80 + g * 16));
    }

    // PV: V fragment read once, used by both row-groups
#pragma unroll
    for (int nO = 0; nO < 8; ++nO) {
      bf16x8 vf = __builtin_bit_cast(bf16x8,
          *(const u16x8*)(bb + 8192 + (nO * 16 + c) * 64 + ((g ^ (c & 3)) << 4)));
      acc[0][nO] = mfma16(pf[0], vf, acc[0][nO]);
      acc[1][nO] = mfma16(pf[1], vf, acc[1][nO]);
    }
    __syncthreads();
  }

  // redistribute L (per-lane q-row c) to O layout (rows g*4+r)
  float Li[2][4];
#pragma unroll
  for (int rg = 0; rg < 2; ++rg)
#pragma unroll
    for (int r = 0; r < 4; ++r) Li[rg][r] = __shfl(L_r[rg], g * 4 + r);

  const float lam = lamp[0];
  float* comb = (float*)smem;   // [64][132] f32
  if (p == 1) {
#pragma unroll
    for (int rg = 0; rg < 2; ++rg)
#pragma unroll
      for (int r = 0; r < 4; ++r) {
        float inv = 1.f / Li[rg][r];
#pragma unroll
        for (int nO = 0; nO < 8; ++nO)
          comb[(sg * 32 + rg * 16 + g * 4 + r) * 132 + nO * 16 + c] = acc[rg][nO][r] * inv;
      }
  }
  __syncthreads();
  if (p == 0) {
    float lw[8], lb[8];
#pragma unroll
    for (int nO = 0; nO < 8; ++nO) {
      lw[nO] = lnw[nO * 16 + c];
      lb[nO] = lnb[nO * 16 + c];
    }
#pragma unroll
    for (int rg = 0; rg < 2; ++rg)
#pragma unroll
      for (int r = 0; r < 4; ++r) {
        float inv1 = 1.f / Li[rg][r];
        float vals[8];
        float ss = 0.f;
#pragma unroll
        for (int nO = 0; nO < 8; ++nO) {
          float o2 = comb[(sg * 32 + rg * 16 + g * 4 + r) * 132 + nO * 16 + c];
          float v = acc[rg][nO][r] * inv1 - lam * o2;
          vals[nO] = v;
          ss += v * v;
        }
        ss += __shfl_xor(ss, 1);
        ss += __shfl_xor(ss, 2);
        ss += __shfl_xor(ss, 4);
        ss += __shfl_xor(ss, 8);
        float rinv = rsqrtf(ss * (1.0f / 128.0f) + 1e-8f);
        int srow = b * 2048 + qt * 64 + sg * 32 + rg * 16 + g * 4 + r;
#pragma unroll
        for (int nO = 0; nO < 8; ++nO) {
          float v = (vals[nO] * rinv * lw[nO] + lb[nO]) * ONE_MINUS_LI;
          Oc[(size_t)srow * 1024 + h * 128 + nO * 16 + c] = b16(v);
        }
      }
  }
}

extern "C" void kernel_launch(void* const* d_in, const int* in_sizes, int n_in,
                              void* d_out, int out_size, void* d_ws, size_t ws_size,
                              hipStream_t stream) {
  const float* x   = (const float*)d_in[0];
  const float* Wq  = (const float*)d_in[1];
  const float* Wk  = (const float*)d_in[2];
  const float* Wv  = (const float*)d_in[3];
  const float* Wo  = (const float*)d_in[4];
  const float* lq1 = (const float*)d_in[5];
  const float* lk1 = (const float*)d_in[6];
  const float* lq2 = (const float*)d_in[7];
  const float* lk2 = (const float*)d_in[8];
  const float* lnw = (const float*)d_in[9];
  const float* lnb = (const float*)d_in[10];

  char* w = (char*)d_ws;
  size_t off = 0;
  auto alloc = [&](size_t bytes) {
    char* pp = w + off;
    off = (off + bytes + 255) & ~(size_t)255;
    return pp;
  };
  u16* xb   = (u16*)alloc(4096ull * 1024 * 2);
  u16* wqb  = (u16*)alloc(1024ull * 1024 * 2);
  u16* wkb  = (u16*)alloc(1024ull * 1024 * 2);
  u16* wvb  = (u16*)alloc(1024ull * 1024 * 2);
  u16* wob  = (u16*)alloc(1024ull * 1024 * 2);
  u16* Qb   = (u16*)alloc(4096ull * 1024 * 2);
  u16* Kb   = (u16*)alloc(4096ull * 1024 * 2);
  u16* Vb   = (u16*)alloc(4096ull * 1024 * 2);
  u16* Vt   = (u16*)alloc(4096ull * 1024 * 2);
  u16* Ocb  = (u16*)alloc(4096ull * 1024 * 2);
  float* cosT = (float*)alloc(2048ull * 32 * 4);
  float* sinT = (float*)alloc(2048ull * 32 * 4);
  float* lamp = (float*)alloc(256);

  prep_kernel<<<8449, 256, 0, stream>>>(x, Wq, Wk, Wv, Wo, lq1, lk1, lq2, lk2,
                                        xb, wqb, wkb, wvb, wob, cosT, sinT, lamp);

  gemm_qkv_kernel<<<dim3(32, 8, 3), 256, 0, stream>>>(xb, wqb, wkb, wvb, Qb, Kb, Vb);

  rope_kernel<<<4096, 256, 0, stream>>>(Qb, Kb, cosT, sinT);

  transpose_v_kernel<<<dim3(32, 16), 256, 0, stream>>>(Vb, Vt);

  attn_kernel<<<512, 256, 0, stream>>>(Qb, Kb, Vt, lamp, lnw, lnb, Ocb);

  gemm_f32_kernel<<<dim3(32, 8), 256, 0, stream>>>(Ocb, wob, (float*)d_out);
}